// Round 12
// baseline (128.639 us; speedup 1.0000x reference)
//
#include <hip/hip_runtime.h>

#define BB 4
#define CCH 64
#define HH 256
#define WW 256
#define PP (HH*WW)     // 65536
#define NS 256         // nh*nw = 16*16

// rel[k] = (k/3 - 1)*16 + (k%3 - 1)  -> {-17,-16,-15,-1,0,1,15,16,17}

// ---------------- Kernel A: superpixel means -> spix[b][s][c] ----------------
__global__ __launch_bounds__(256) void kA_spix_init(const float* __restrict__ x,
                                                    float* __restrict__ spix) {
    int blk = blockIdx.x;          // 4*64*16
    int i = blk & 15;              // superpixel row
    int c = (blk >> 4) & 63;
    int b = blk >> 10;
    int t = threadIdx.x;           // column 0..255
    const float* base = x + ((size_t)(b*CCH + c))*PP + (size_t)i*16*WW + t;
    float s = 0.f;
    #pragma unroll
    for (int r = 0; r < 16; ++r) s += base[(size_t)r*WW];
    #pragma unroll
    for (int off = 8; off; off >>= 1) s += __shfl_down(s, off, 16);
    if ((t & 15) == 0) {
        int j = t >> 4;
        spix[((size_t)b*NS + (i*16 + j))*CCH + c] = s * (1.f/256.f);
    }
}

// ---------------- Kernel Fdot: iter-0 aff only -> aff9[b][k][p] (row-major) --
// Identical front to kBE (proven cheap); stores 9 coalesced row-planes.
__global__ __launch_bounds__(256) void kFdot(const float* __restrict__ x,
                                             const float* __restrict__ spix,
                                             float* __restrict__ aff9) {
    __shared__ float spw[50][68];
    __shared__ float snw[50];
    int blk = blockIdx.x;           // B*H = 1024
    int y = blk & 255;
    int b = blk >> 8;
    int t = threadIdx.x;            // x coordinate
    int ly = y >> 4;
    int base = ly*16 - 17;

    for (int idx = t; idx < 50*CCH; idx += 256) {
        int j = idx >> 6, c = idx & 63;
        int g = base + j;
        float v = 0.f;
        if (g >= 0 && g < NS) v = spix[((size_t)b*NS + g)*CCH + c];
        spw[j][c] = v;
    }
    __syncthreads();
    if (t < 50) {
        float s = 0.f;
        #pragma unroll
        for (int c4 = 0; c4 < 16; ++c4) {
            float4 v = *reinterpret_cast<const float4*>(&spw[t][c4*4]);
            s += v.x*v.x + v.y*v.y + v.z*v.z + v.w*v.w;
        }
        snw[t] = s;
    }
    __syncthreads();

    int p = y*WW + t;
    const float* px = x + (size_t)b*CCH*PP + p;
    int wl = 17 + (t >> 4);
    int nk[9];
    #pragma unroll
    for (int k = 0; k < 9; ++k) nk[k] = wl + (k/3 - 1)*16 + (k%3 - 1);

    float cross[9];
    #pragma unroll
    for (int k = 0; k < 9; ++k) cross[k] = 0.f;
    float pn = 0.f;
    #pragma unroll
    for (int cc = 0; cc < 16; ++cc) {
        float v0 = px[(size_t)(cc*4+0)*PP];
        float v1 = px[(size_t)(cc*4+1)*PP];
        float v2 = px[(size_t)(cc*4+2)*PP];
        float v3 = px[(size_t)(cc*4+3)*PP];
        pn += v0*v0 + v1*v1 + v2*v2 + v3*v3;
        #pragma unroll
        for (int k = 0; k < 9; ++k) {
            const float4 s = *reinterpret_cast<const float4*>(&spw[nk[k]][cc*4]);
            cross[k] += s.x*v0 + s.y*v1 + s.z*v2 + s.w*v3;
        }
    }

    int label = ly*16 + (t >> 4);
    float e[9];
    float m = -1e30f;
    #pragma unroll
    for (int k = 0; k < 9; ++k) {
        int rel = (k/3 - 1)*16 + (k%3 - 1);
        int sidx = label + rel;
        bool valid = (sidx >= 0) && (sidx < NS);
        float z = -(pn - 2.f*cross[k] + snw[nk[k]]);
        e[k] = valid ? z : -3.0e38f;
        if (valid && z > m) m = z;
    }
    float sum = 0.f;
    #pragma unroll
    for (int k = 0; k < 9; ++k) {
        float v = (e[k] > -2.9e38f) ? expf(e[k] - m) : 0.f;
        e[k] = v;
        sum += v;
    }
    float inv = 1.f / sum;
    #pragma unroll
    for (int k = 0; k < 9; ++k)
        aff9[((size_t)b*9 + k)*PP + p] = e[k] * inv;
}

// ---------------- Kernel P: register-accumulated partials (no LDS) ----------
// Block = (b, ly, cq): 4 channels x one 16-row tile band. Thread t = column.
// Per row: coalesced 1KB reads of 9 aff rows + 4 x rows; per-lane FMA into
// acc[9][4]; one width-16 segmented shuffle reduce at the end.
__global__ __launch_bounds__(256) void kP(const float* __restrict__ x,
                                          const float* __restrict__ aff9,
                                          float* __restrict__ partial,
                                          float* __restrict__ wpart) {
    int blk = blockIdx.x;            // b*256 + ly*16 + cq   (4096... no: 4*16*16=1024)
    int cq = blk & 15, ly = (blk >> 4) & 15, b = blk >> 8;
    int t = threadIdx.x;             // image column
    int c0 = cq*4;
    const float* xb = x + (size_t)b*CCH*PP;
    const float* ab = aff9 + (size_t)b*9*PP;

    float acc[9][4];
    #pragma unroll
    for (int k = 0; k < 9; ++k)
        #pragma unroll
        for (int dc = 0; dc < 4; ++dc) acc[k][dc] = 0.f;
    float accw[9];
    #pragma unroll
    for (int k = 0; k < 9; ++k) accw[k] = 0.f;

    #pragma unroll 4
    for (int r = 0; r < 16; ++r) {
        int p = (ly*16 + r)*WW + t;
        float a[9];
        #pragma unroll
        for (int k = 0; k < 9; ++k) a[k] = ab[(size_t)k*PP + p];
        #pragma unroll
        for (int k = 0; k < 9; ++k) accw[k] += a[k];
        #pragma unroll
        for (int dc = 0; dc < 4; ++dc) {
            float xv = xb[(size_t)(c0 + dc)*PP + p];
            #pragma unroll
            for (int k = 0; k < 9; ++k) acc[k][dc] += a[k]*xv;
        }
    }

    // width-16 segmented reduce (columns of one tile)
    #pragma unroll
    for (int k = 0; k < 9; ++k) {
        #pragma unroll
        for (int dc = 0; dc < 4; ++dc) {
            float v = acc[k][dc];
            v += __shfl_down(v, 8, 16);
            v += __shfl_down(v, 4, 16);
            v += __shfl_down(v, 2, 16);
            v += __shfl_down(v, 1, 16);
            acc[k][dc] = v;
        }
    }
    if ((t & 15) == 0) {
        int l = ly*16 + (t >> 4);
        #pragma unroll
        for (int k = 0; k < 9; ++k)
            #pragma unroll
            for (int dc = 0; dc < 4; ++dc)
                partial[(((size_t)b*9 + k)*NS + l)*CCH + c0 + dc] = acc[k][dc];
    }
    if (cq == 0) {
        #pragma unroll
        for (int k = 0; k < 9; ++k) {
            float v = accw[k];
            v += __shfl_down(v, 8, 16);
            v += __shfl_down(v, 4, 16);
            v += __shfl_down(v, 2, 16);
            v += __shfl_down(v, 1, 16);
            if ((t & 15) == 0)
                wpart[((size_t)b*9 + k)*NS + (ly*16 + (t >> 4))] = v;
        }
    }
}

// ---------------- Kernel D: gather + divide -> new spix ---------------------
__global__ __launch_bounds__(256) void kD_update(const float* __restrict__ partial,
                                                 const float* __restrict__ wpart,
                                                 float* __restrict__ spix) {
    int gid = blockIdx.x*256 + threadIdx.x;   // 65536
    int c = gid & 63, s = (gid >> 6) & 255, b = gid >> 14;
    float num = 0.f, den = 0.f;
    #pragma unroll
    for (int k = 0; k < 9; ++k) {
        int rel = (k/3 - 1)*16 + (k%3 - 1);
        int l = s - rel;
        if (l >= 0 && l < NS) {
            num += partial[(((size_t)b*9 + k)*NS + l)*CCH + c];
            den += wpart[((size_t)b*9 + k)*NS + l];
        }
    }
    spix[((size_t)b*NS + s)*CCH + c] = num / (den + 1e-16f);
}

// ---------------- Kernel BE: fused final aff + dense output write -----------
__global__ __launch_bounds__(256) void kBE(const float* __restrict__ x,
                                           const float* __restrict__ spix,
                                           float* __restrict__ out,
                                           int out_size) {
    __shared__ float spw[50][68];
    __shared__ float snw[50];
    __shared__ float affL[9][260];
    int blk = blockIdx.x;           // B*H = 1024
    int y = blk & 255;
    int b = blk >> 8;
    int t = threadIdx.x;            // x coordinate
    int ly = y >> 4;
    int base = ly*16 - 17;

    for (int idx = t; idx < 50*CCH; idx += 256) {
        int j = idx >> 6, c = idx & 63;
        int g = base + j;
        float v = 0.f;
        if (g >= 0 && g < NS) v = spix[((size_t)b*NS + g)*CCH + c];
        spw[j][c] = v;
    }
    __syncthreads();
    if (t < 50) {
        float s = 0.f;
        #pragma unroll
        for (int c4 = 0; c4 < 16; ++c4) {
            float4 v = *reinterpret_cast<const float4*>(&spw[t][c4*4]);
            s += v.x*v.x + v.y*v.y + v.z*v.z + v.w*v.w;
        }
        snw[t] = s;
    }
    __syncthreads();

    int p = y*WW + t;
    const float* px = x + (size_t)b*CCH*PP + p;
    int wl = 17 + (t >> 4);
    int nk[9];
    #pragma unroll
    for (int k = 0; k < 9; ++k) nk[k] = wl + (k/3 - 1)*16 + (k%3 - 1);

    float cross[9];
    #pragma unroll
    for (int k = 0; k < 9; ++k) cross[k] = 0.f;
    float pn = 0.f;
    #pragma unroll
    for (int cc = 0; cc < 16; ++cc) {
        float v0 = px[(size_t)(cc*4+0)*PP];
        float v1 = px[(size_t)(cc*4+1)*PP];
        float v2 = px[(size_t)(cc*4+2)*PP];
        float v3 = px[(size_t)(cc*4+3)*PP];
        pn += v0*v0 + v1*v1 + v2*v2 + v3*v3;
        #pragma unroll
        for (int k = 0; k < 9; ++k) {
            const float4 s = *reinterpret_cast<const float4*>(&spw[nk[k]][cc*4]);
            cross[k] += s.x*v0 + s.y*v1 + s.z*v2 + s.w*v3;
        }
    }

    int label = ly*16 + (t >> 4);
    float e[9];
    float m = -1e30f;
    #pragma unroll
    for (int k = 0; k < 9; ++k) {
        int rel = (k/3 - 1)*16 + (k%3 - 1);
        int sidx = label + rel;
        bool valid = (sidx >= 0) && (sidx < NS);
        float z = -(pn - 2.f*cross[k] + snw[nk[k]]);
        e[k] = valid ? z : -3.0e38f;
        if (valid && z > m) m = z;
    }
    float sum = 0.f;
    #pragma unroll
    for (int k = 0; k < 9; ++k) {
        float v = (e[k] > -2.9e38f) ? expf(e[k] - m) : 0.f;
        e[k] = v;
        sum += v;
    }
    float inv = 1.f / sum;
    #pragma unroll
    for (int k = 0; k < 9; ++k) affL[k][t] = e[k] * inv;
    __syncthreads();

    // ---- dense write: wave w writes rows s ≡ w (mod 4), 1 KB per store row
    int w = t >> 6, lane = t & 63;
    int px4 = lane * 4;
    int labelbase = ly*16 + (px4 >> 4);
    float* orow = out + (size_t)b*NS*PP + (size_t)y*WW + px4;
    #pragma unroll 8
    for (int r = 0; r < 64; ++r) {
        int s = w + 4*r;
        int diff = s - labelbase + 17;
        float4 v = make_float4(0.f, 0.f, 0.f, 0.f);
        if ((unsigned)diff <= 34u && (diff & 15) < 3) {
            int k = (diff >> 4)*3 + (diff & 15);
            v = *(const float4*)&affL[k][px4];
        }
        *(float4*)(orow + (size_t)s*PP) = v;
    }
    if (blk == 0 && t == 0) out[out_size - 1] = 256.0f;   // Output 1: ns
}

extern "C" void kernel_launch(void* const* d_in, const int* in_sizes, int n_in,
                              void* d_out, int out_size, void* d_ws, size_t ws_size,
                              hipStream_t stream) {
    (void)in_sizes; (void)n_in; (void)ws_size;
    const float* x = (const float*)d_in[0];
    float* out = (float*)d_out;
    float* ws = (float*)d_ws;

    float* spix    = ws;                            // 65,536 floats
    float* aff9    = spix + (size_t)BB*NS*CCH;      // 2,359,296 floats
    float* partial = aff9 + (size_t)BB*9*PP;        // 589,824 floats
    float* wpart   = partial + (size_t)BB*9*NS*CCH; // 9,216 floats

    kA_spix_init<<<BB*CCH*16, 256, 0, stream>>>(x, spix);
    kFdot<<<BB*HH, 256, 0, stream>>>(x, spix, aff9);
    kP<<<BB*16*16, 256, 0, stream>>>(x, aff9, partial, wpart);
    kD_update<<<BB*NS*CCH/256, 256, 0, stream>>>(partial, wpart, spix);
    kBE<<<BB*HH, 256, 0, stream>>>(x, spix, out, out_size);
}